// Round 1
// baseline (6070.867 us; speedup 1.0000x reference)
//
#include <hip/hip_runtime.h>

typedef _Float16 f16;
typedef __attribute__((ext_vector_type(8))) _Float16 f16x8;
typedef __attribute__((ext_vector_type(4))) float f32x4;

#define BD 64      // state dim D
#define HW 512     // hidden width W
#define TT 16      // time points T
#define BR 16      // batch rows per block
#define NBLK 32    // 512 / 16
#define NTHREADS 512

// Tsit5 coefficients
constexpr float cA21 = 0.161f;
constexpr float cA31 = -0.008480655492356989f, cA32 = 0.335480655492357f;
constexpr float cA41 = 2.8971530571054935f, cA42 = -6.359448489975075f, cA43 = 4.3622954328695815f;
constexpr float cA51 = 5.325864828439257f, cA52 = -11.748883564062828f, cA53 = 7.4955393428898365f, cA54 = -0.09249506636175525f;
constexpr float cA61 = 5.86145544294642f, cA62 = -12.92096931784711f, cA63 = 8.159367898576159f, cA64 = -0.071584973281401f, cA65 = -0.028269050394068383f;
constexpr float cB1 = 0.09646076681806523f, cB2 = 0.01f, cB3 = 0.4798896504144996f;
constexpr float cB4 = 1.379008574103742f, cB5 = -3.290069515436081f, cB6 = 2.324710524099774f;

__device__ __forceinline__ float softplus_f(float x) {
  // matches jax.nn.softplus = max(x,0) + log1p(exp(-|x|)); tolerance is loose (2%)
  return fmaxf(x, 0.0f) + __logf(1.0f + __expf(-fabsf(x)));
}

// convert W0 [512,64], W1 [512,512], W2 [64,512] (row-major f32) to fp16 in ws
__global__ void cvt_kernel(const float* __restrict__ w0,
                           const float* __restrict__ w1,
                           const float* __restrict__ w2,
                           f16* __restrict__ wsh) {
  int i = blockIdx.x * 512 + threadIdx.x;
  if (i < 32768) wsh[i] = (f16)w0[i];
  else if (i < 294912) wsh[i] = (f16)w1[i - 32768];
  else if (i < 327680) wsh[i] = (f16)w2[i - 294912];
}

__global__ __launch_bounds__(NTHREADS)
void ode_kernel(const float* __restrict__ ts,
                const float* __restrict__ y0,
                const float* __restrict__ b0,
                const float* __restrict__ b1,
                const float* __restrict__ b2,
                const f16* __restrict__ W0h,
                const f16* __restrict__ W1h,
                const f16* __restrict__ W2h,
                float* __restrict__ out) {
  // activations (fp16, +8 f16 pad = 16B so ds_read_b128 rows land 2-way max)
  __shared__ __align__(16) f16 h0buf[BR][HW + 8];
  __shared__ __align__(16) f16 h1buf[BR][HW + 8];
  __shared__ __align__(16) f16 atile[BR][BD + 8];
  // f32 integrator state
  __shared__ float kbuf[6][BR][BD];
  __shared__ float ybuf[BR][BD];
  __shared__ float redbuf[4][BR][16];

  const int tid = threadIdx.x;
  const int wave = tid >> 6;
  const int lane = tid & 63;
  const int m = lane & 15;   // A-row / B-col / D-col index
  const int g = lane >> 4;   // lane group 0..3
  const int row0 = blockIdx.x * BR;

  // load y0 rows into LDS, write t=0 output
  for (int e = tid; e < BR * BD; e += NTHREADS) {
    const int r = e >> 6, d = e & 63;
    const float v = y0[(row0 + r) * BD + d];
    ybuf[r][d] = v;
    out[(row0 + r) * (TT * BD) + d] = v;
  }
  __syncthreads();

  // f(atile) -> kdst  (one MLP eval for this block's 16 rows)
  auto feval = [&](float (*kdst)[BD]) {
    const int cbase = wave * 64;
    // ---- layer 1: h0 = softplus(atile @ W0^T + b0), each wave owns 64 cols
    {
      f32x4 acc[4] = {{0.f,0.f,0.f,0.f},{0.f,0.f,0.f,0.f},{0.f,0.f,0.f,0.f},{0.f,0.f,0.f,0.f}};
#pragma unroll
      for (int kt = 0; kt < 2; ++kt) {
        const f16x8 a = *(const f16x8*)&atile[m][kt * 32 + g * 8];
#pragma unroll
        for (int nt = 0; nt < 4; ++nt) {
          const f16x8 b = *(const f16x8*)&W0h[(cbase + nt * 16 + m) * BD + kt * 32 + g * 8];
          acc[nt] = __builtin_amdgcn_mfma_f32_16x16x32_f16(a, b, acc[nt], 0, 0, 0);
        }
      }
#pragma unroll
      for (int nt = 0; nt < 4; ++nt) {
        const int n = cbase + nt * 16 + m;
        const float bias = b0[n];
#pragma unroll
        for (int j = 0; j < 4; ++j)
          h0buf[g * 4 + j][n] = (f16)softplus_f(acc[nt][j] + bias);
      }
    }
    __syncthreads();
    // ---- layer 2: h1 = softplus(h0 @ W1^T + b1)
    {
      f32x4 acc[4] = {{0.f,0.f,0.f,0.f},{0.f,0.f,0.f,0.f},{0.f,0.f,0.f,0.f},{0.f,0.f,0.f,0.f}};
#pragma unroll 4
      for (int kt = 0; kt < 16; ++kt) {
        const f16x8 a = *(const f16x8*)&h0buf[m][kt * 32 + g * 8];
#pragma unroll
        for (int nt = 0; nt < 4; ++nt) {
          const f16x8 b = *(const f16x8*)&W1h[(cbase + nt * 16 + m) * HW + kt * 32 + g * 8];
          acc[nt] = __builtin_amdgcn_mfma_f32_16x16x32_f16(a, b, acc[nt], 0, 0, 0);
        }
      }
#pragma unroll
      for (int nt = 0; nt < 4; ++nt) {
        const int n = cbase + nt * 16 + m;
        const float bias = b1[n];
#pragma unroll
        for (int j = 0; j < 4; ++j)
          h1buf[g * 4 + j][n] = (f16)softplus_f(acc[nt][j] + bias);
      }
    }
    __syncthreads();
    // ---- layer 3: k = h1 @ W2^T + b2  (split-K across wave pairs)
    {
      const int ntile = wave & 3;  // output col tile (16 cols)
      const int kh = wave >> 2;    // K half
      f32x4 acc = {0.f, 0.f, 0.f, 0.f};
#pragma unroll
      for (int kt = 0; kt < 8; ++kt) {
        const int k = kh * 256 + kt * 32 + g * 8;
        const f16x8 a = *(const f16x8*)&h1buf[m][k];
        const f16x8 b = *(const f16x8*)&W2h[(ntile * 16 + m) * HW + k];
        acc = __builtin_amdgcn_mfma_f32_16x16x32_f16(a, b, acc, 0, 0, 0);
      }
      if (kh == 1) {
#pragma unroll
        for (int j = 0; j < 4; ++j) redbuf[ntile][g * 4 + j][m] = acc[j];
      }
      __syncthreads();
      if (kh == 0) {
        const float bias = b2[ntile * 16 + m];
#pragma unroll
        for (int j = 0; j < 4; ++j)
          kdst[g * 4 + j][ntile * 16 + m] = acc[j] + redbuf[ntile][g * 4 + j][m] + bias;
      }
    }
    __syncthreads();
  };

#define KV(j) kbuf[j][r][d]
#define COMBINE(EXPR)                                   \
  for (int e = tid; e < BR * BD; e += NTHREADS) {       \
    const int r = e >> 6, d = e & 63;                   \
    const float yv = ybuf[r][d];                        \
    atile[r][d] = (f16)(EXPR);                          \
  }                                                     \
  __syncthreads();

  for (int t = 0; t < TT - 1; ++t) {
    const float hstep = (ts[t + 1] - ts[t]) * 0.25f;
    for (int s = 0; s < 4; ++s) {
      COMBINE(yv)
      feval(kbuf[0]);
      COMBINE(yv + hstep * (cA21 * KV(0)))
      feval(kbuf[1]);
      COMBINE(yv + hstep * (cA31 * KV(0) + cA32 * KV(1)))
      feval(kbuf[2]);
      COMBINE(yv + hstep * (cA41 * KV(0) + cA42 * KV(1) + cA43 * KV(2)))
      feval(kbuf[3]);
      COMBINE(yv + hstep * (cA51 * KV(0) + cA52 * KV(1) + cA53 * KV(2) + cA54 * KV(3)))
      feval(kbuf[4]);
      COMBINE(yv + hstep * (cA61 * KV(0) + cA62 * KV(1) + cA63 * KV(2) + cA64 * KV(3) + cA65 * KV(4)))
      feval(kbuf[5]);
      // y update
      for (int e = tid; e < BR * BD; e += NTHREADS) {
        const int r = e >> 6, d = e & 63;
        ybuf[r][d] += hstep * (cB1 * KV(0) + cB2 * KV(1) + cB3 * KV(2) +
                               cB4 * KV(3) + cB5 * KV(4) + cB6 * KV(5));
      }
      __syncthreads();
    }
    // save y at t+1
    for (int e = tid; e < BR * BD; e += NTHREADS) {
      const int r = e >> 6, d = e & 63;
      out[(row0 + r) * (TT * BD) + (t + 1) * BD + d] = ybuf[r][d];
    }
  }
#undef KV
#undef COMBINE
}

extern "C" void kernel_launch(void* const* d_in, const int* in_sizes, int n_in,
                              void* d_out, int out_size, void* d_ws, size_t ws_size,
                              hipStream_t stream) {
  const float* ts = (const float*)d_in[0];
  const float* y0 = (const float*)d_in[1];
  const float* W0 = (const float*)d_in[2];
  const float* b0 = (const float*)d_in[3];
  const float* W1 = (const float*)d_in[4];
  const float* b1 = (const float*)d_in[5];
  const float* W2 = (const float*)d_in[6];
  const float* b2 = (const float*)d_in[7];
  f16* wsh = (f16*)d_ws;  // needs 655360 bytes: W0h | W1h | W2h

  cvt_kernel<<<640, 512, 0, stream>>>(W0, W1, W2, wsh);
  ode_kernel<<<NBLK, NTHREADS, 0, stream>>>(ts, y0, b0, b1, b2,
                                            wsh, wsh + 32768, wsh + 294912,
                                            (float*)d_out);
}

// Round 2
// 3351.651 us; speedup vs baseline: 1.8113x; 1.8113x over previous
//
#include <hip/hip_runtime.h>

typedef _Float16 f16;
typedef __attribute__((ext_vector_type(8))) _Float16 f16x8;
typedef __attribute__((ext_vector_type(4))) float f32x4;

#define BD 64      // state dim D
#define HW 512     // hidden width W
#define TT 16      // time points T
#define BR 16      // batch rows per block
#define NBLK 32    // 512 / 16
#define NTHREADS 512

// Tsit5 coefficients
constexpr float cA21 = 0.161f;
constexpr float cA31 = -0.008480655492356989f, cA32 = 0.335480655492357f;
constexpr float cA41 = 2.8971530571054935f, cA42 = -6.359448489975075f, cA43 = 4.3622954328695815f;
constexpr float cA51 = 5.325864828439257f, cA52 = -11.748883564062828f, cA53 = 7.4955393428898365f, cA54 = -0.09249506636175525f;
constexpr float cA61 = 5.86145544294642f, cA62 = -12.92096931784711f, cA63 = 8.159367898576159f, cA64 = -0.071584973281401f, cA65 = -0.028269050394068383f;
constexpr float cB1 = 0.09646076681806523f, cB2 = 0.01f, cB3 = 0.4798896504144996f;
constexpr float cB4 = 1.379008574103742f, cB5 = -3.290069515436081f, cB6 = 2.324710524099774f;

__device__ __forceinline__ float softplus_f(float x) {
  return fmaxf(x, 0.0f) + __logf(1.0f + __expf(-fabsf(x)));
}

// convert W0 [512,64], W1 [512,512], W2 [64,512] (row-major f32) to fp16 in ws
__global__ void cvt_kernel(const float* __restrict__ w0,
                           const float* __restrict__ w1,
                           const float* __restrict__ w2,
                           f16* __restrict__ wsh) {
  int i = blockIdx.x * 512 + threadIdx.x;
  if (i < 32768) wsh[i] = (f16)w0[i];
  else if (i < 294912) wsh[i] = (f16)w1[i - 32768];
  else if (i < 327680) wsh[i] = (f16)w2[i - 294912];
}

__global__ __launch_bounds__(NTHREADS, 2)   // 1 block/CU: allow 256 VGPRs/wave
void ode_kernel(const float* __restrict__ ts,
                const float* __restrict__ y0,
                const float* __restrict__ b0,
                const float* __restrict__ b1,
                const float* __restrict__ b2,
                const f16* __restrict__ W0h,
                const f16* __restrict__ W1h,
                const f16* __restrict__ W2h,
                float* __restrict__ out) {
  __shared__ __align__(16) f16 h0buf[BR][HW + 8];
  __shared__ __align__(16) f16 h1buf[BR][HW + 8];
  __shared__ __align__(16) f16 atile[BR][BD + 8];
  // k stored as two K-halves (split-K layer 3, no reduce barrier); summed in COMBINE
  __shared__ float kbuf[2][6][BR][BD];
  __shared__ float ybuf[BR][BD];

  const int tid = threadIdx.x;
  const int wave = tid >> 6;
  const int lane = tid & 63;
  const int m = lane & 15;   // A-row / B-col / D-col index
  const int g = lane >> 4;   // lane group 0..3
  const int row0 = blockIdx.x * BR;
  const int cbase = wave * 64;   // layer1/2 output-column base for this wave
  const int ntile = wave & 3;    // layer3 output col tile
  const int kh = wave >> 2;      // layer3 K half

  // ---- preload loop-invariant weights/biases into registers ----
  f16x8 w0r[2][4];                       // 32 VGPR
#pragma unroll
  for (int kt = 0; kt < 2; ++kt)
#pragma unroll
    for (int nt = 0; nt < 4; ++nt)
      w0r[kt][nt] = *(const f16x8*)&W0h[(cbase + nt * 16 + m) * BD + kt * 32 + g * 8];
  f16x8 w2r[8];                          // 32 VGPR (per-wave K-half of W2 tile)
#pragma unroll
  for (int kt = 0; kt < 8; ++kt)
    w2r[kt] = *(const f16x8*)&W2h[(ntile * 16 + m) * HW + kh * 256 + kt * 32 + g * 8];
  float bias0[4], bias1[4];
#pragma unroll
  for (int nt = 0; nt < 4; ++nt) {
    bias0[nt] = b0[cbase + nt * 16 + m];
    bias1[nt] = b1[cbase + nt * 16 + m];
  }
  const float bias2 = (kh == 0) ? b2[ntile * 16 + m] : 0.0f;

  // ---- init: y0 into LDS (f32) + atile (f16), write t=0 output ----
  for (int e = tid; e < BR * BD; e += NTHREADS) {
    const int r = e >> 6, d = e & 63;
    const float v = y0[(row0 + r) * BD + d];
    ybuf[r][d] = v;
    atile[r][d] = (f16)v;
    out[(row0 + r) * (TT * BD) + d] = v;
  }
  __syncthreads();

  // f(atile) -> kbuf[*][kidx]  (one MLP eval for this block's 16 rows)
  auto feval = [&](int kidx) {
    // ---- layer 1: h0 = softplus(atile @ W0^T + b0); B from registers
    {
      f32x4 acc[4] = {{0.f,0.f,0.f,0.f},{0.f,0.f,0.f,0.f},{0.f,0.f,0.f,0.f},{0.f,0.f,0.f,0.f}};
#pragma unroll
      for (int kt = 0; kt < 2; ++kt) {
        const f16x8 a = *(const f16x8*)&atile[m][kt * 32 + g * 8];
#pragma unroll
        for (int nt = 0; nt < 4; ++nt)
          acc[nt] = __builtin_amdgcn_mfma_f32_16x16x32_f16(a, w0r[kt][nt], acc[nt], 0, 0, 0);
      }
#pragma unroll
      for (int nt = 0; nt < 4; ++nt) {
        const int n = cbase + nt * 16 + m;
#pragma unroll
        for (int j = 0; j < 4; ++j)
          h0buf[g * 4 + j][n] = (f16)softplus_f(acc[nt][j] + bias0[nt]);
      }
    }
    __syncthreads();
    // ---- layer 2: h1 = softplus(h0 @ W1^T + b1); depth-4 register ring prefetch
    {
      f32x4 acc[4] = {{0.f,0.f,0.f,0.f},{0.f,0.f,0.f,0.f},{0.f,0.f,0.f,0.f},{0.f,0.f,0.f,0.f}};
      f16x8 bpre[4][4];                  // 64 VGPR ring
#pragma unroll
      for (int p = 0; p < 4; ++p)
#pragma unroll
        for (int nt = 0; nt < 4; ++nt)
          bpre[p][nt] = *(const f16x8*)&W1h[(cbase + nt * 16 + m) * HW + p * 32 + g * 8];
#pragma unroll
      for (int kt = 0; kt < 16; ++kt) {
        const f16x8 a = *(const f16x8*)&h0buf[m][kt * 32 + g * 8];
#pragma unroll
        for (int nt = 0; nt < 4; ++nt)
          acc[nt] = __builtin_amdgcn_mfma_f32_16x16x32_f16(a, bpre[kt & 3][nt], acc[nt], 0, 0, 0);
        if (kt < 12) {
#pragma unroll
          for (int nt = 0; nt < 4; ++nt)
            bpre[kt & 3][nt] = *(const f16x8*)&W1h[(cbase + nt * 16 + m) * HW + (kt + 4) * 32 + g * 8];
        }
      }
#pragma unroll
      for (int nt = 0; nt < 4; ++nt) {
        const int n = cbase + nt * 16 + m;
#pragma unroll
        for (int j = 0; j < 4; ++j)
          h1buf[g * 4 + j][n] = (f16)softplus_f(acc[nt][j] + bias1[nt]);
      }
    }
    __syncthreads();
    // ---- layer 3: k = h1 @ W2^T + b2; split-K across wave halves, B from registers
    {
      f32x4 acc = {0.f, 0.f, 0.f, 0.f};
#pragma unroll
      for (int kt = 0; kt < 8; ++kt) {
        const f16x8 a = *(const f16x8*)&h1buf[m][kh * 256 + kt * 32 + g * 8];
        acc = __builtin_amdgcn_mfma_f32_16x16x32_f16(a, w2r[kt], acc, 0, 0, 0);
      }
#pragma unroll
      for (int j = 0; j < 4; ++j)
        kbuf[kh][kidx][g * 4 + j][ntile * 16 + m] = acc[j] + bias2;
    }
    __syncthreads();
  };

#define KV(j) (kbuf[0][j][r][d] + kbuf[1][j][r][d])
#define COMBINE(EXPR)                                   \
  for (int e = tid; e < BR * BD; e += NTHREADS) {       \
    const int r = e >> 6, d = e & 63;                   \
    const float yv = ybuf[r][d];                        \
    atile[r][d] = (f16)(EXPR);                          \
  }                                                     \
  __syncthreads();

  for (int t = 0; t < TT - 1; ++t) {
    const float hstep = (ts[t + 1] - ts[t]) * 0.25f;
    for (int s = 0; s < 4; ++s) {
      feval(0);                                          // atile holds current y
      COMBINE(yv + hstep * (cA21 * KV(0)))
      feval(1);
      COMBINE(yv + hstep * (cA31 * KV(0) + cA32 * KV(1)))
      feval(2);
      COMBINE(yv + hstep * (cA41 * KV(0) + cA42 * KV(1) + cA43 * KV(2)))
      feval(3);
      COMBINE(yv + hstep * (cA51 * KV(0) + cA52 * KV(1) + cA53 * KV(2) + cA54 * KV(3)))
      feval(4);
      COMBINE(yv + hstep * (cA61 * KV(0) + cA62 * KV(1) + cA63 * KV(2) + cA64 * KV(3) + cA65 * KV(4)))
      feval(5);
      // merged y-update + stage-1 COMBINE of next substep (atile = y_new)
      for (int e = tid; e < BR * BD; e += NTHREADS) {
        const int r = e >> 6, d = e & 63;
        const float yn = ybuf[r][d] + hstep * (cB1 * KV(0) + cB2 * KV(1) + cB3 * KV(2) +
                                               cB4 * KV(3) + cB5 * KV(4) + cB6 * KV(5));
        ybuf[r][d] = yn;
        atile[r][d] = (f16)yn;
      }
      __syncthreads();
    }
    // save y at t+1 (reads ybuf only; no conflict with next feval's LDS use)
    for (int e = tid; e < BR * BD; e += NTHREADS) {
      const int r = e >> 6, d = e & 63;
      out[(row0 + r) * (TT * BD) + (t + 1) * BD + d] = ybuf[r][d];
    }
  }
#undef KV
#undef COMBINE
}

extern "C" void kernel_launch(void* const* d_in, const int* in_sizes, int n_in,
                              void* d_out, int out_size, void* d_ws, size_t ws_size,
                              hipStream_t stream) {
  const float* ts = (const float*)d_in[0];
  const float* y0 = (const float*)d_in[1];
  const float* W0 = (const float*)d_in[2];
  const float* b0 = (const float*)d_in[3];
  const float* W1 = (const float*)d_in[4];
  const float* b1 = (const float*)d_in[5];
  const float* W2 = (const float*)d_in[6];
  const float* b2 = (const float*)d_in[7];
  f16* wsh = (f16*)d_ws;  // needs 655360 bytes: W0h | W1h | W2h

  cvt_kernel<<<640, 512, 0, stream>>>(W0, W1, W2, wsh);
  ode_kernel<<<NBLK, NTHREADS, 0, stream>>>(ts, y0, b0, b1, b2,
                                            wsh, wsh + 32768, wsh + 294912,
                                            (float*)d_out);
}